// Round 3
// baseline (94.187 us; speedup 1.0000x reference)
//
#include <hip/hip_runtime.h>

#define BB  256
#define LL  512
#define DD  64
#define NID 10000
#define NW  (NID / 2)        // packed u16 pairs per histogram
#define NROWS (2 * BB * LL)  // 262144 output rows
#define NT4  (NROWS * 16)    // 4194304 float4s of output

// ---- Kernel A: T[a][e] = sum_d relu(a*W1[d]+b1[d]) * W2[e][d] + b2[e], a in [0,512]
// 256 threads = 4 waves; wave w handles a = blockIdx*4 + w. W2 staged in LDS
// with +1 pad -> bank (e+d)&31, 2-way aliasing (free).
__global__ __launch_bounds__(256) void build_table(
    const float* __restrict__ W1, const float* __restrict__ b1,
    const float* __restrict__ W2, const float* __restrict__ b2,
    float* __restrict__ T)
{
    __shared__ float w2l[DD][DD + 1];
    __shared__ float hsh[4][DD];
    const int t = threadIdx.x;
    const int w = t >> 6;
    const int e = t & 63;
    for (int i = t; i < DD * DD; i += 256)
        w2l[i >> 6][i & 63] = W2[i];
    const int a = blockIdx.x * 4 + w;   // 0..515
    hsh[w][e] = fmaxf((float)a * W1[e] + b1[e], 0.0f);
    __syncthreads();
    if (a <= LL) {
        float acc = b2[e];
#pragma unroll
        for (int d = 0; d < DD; ++d)
            acc = fmaf(hsh[w][d], w2l[e][d], acc);
        T[a * DD + e] = acc;
    }
}

// ---- Kernel B1: per-batch packed-u16 histograms -> per-row packed counts.
// One block per batch. Emits R[row] = (count-in-src-hist) | (count-in-dst-hist << 16).
// Rows 0..BB*LL-1 = src positions, BB*LL.. = dst positions.
__global__ __launch_bounds__(512) void count_rows(
    const int* __restrict__ src_ids, const int* __restrict__ dst_ids,
    unsigned int* __restrict__ R)
{
    __shared__ unsigned int hs[NW];
    __shared__ unsigned int hd[NW];
    const int t = threadIdx.x;
    const int b = blockIdx.x;

    uint4* z1 = (uint4*)hs;
    uint4* z2 = (uint4*)hd;
    const uint4 z = make_uint4(0u, 0u, 0u, 0u);
    for (int i = t; i < NW / 4; i += 512) { z1[i] = z; z2[i] = z; }
    const int sid = src_ids[b * LL + t];
    const int did = dst_ids[b * LL + t];
    __syncthreads();

    atomicAdd(&hs[sid >> 1], 1u << ((sid & 1) * 16));
    atomicAdd(&hd[did >> 1], 1u << ((did & 1) * 16));
    __syncthreads();

    unsigned int c_ss = (hs[sid >> 1] >> ((sid & 1) * 16)) & 0xFFFFu;
    unsigned int c_sd = (hd[sid >> 1] >> ((sid & 1) * 16)) & 0xFFFFu;
    unsigned int c_ds = (hs[did >> 1] >> ((did & 1) * 16)) & 0xFFFFu;
    unsigned int c_dd = (hd[did >> 1] >> ((did & 1) * 16)) & 0xFFFFu;
    if (sid == 0) { c_ss = 0u; c_sd = 0u; }   // padding id==0 -> app forced to 0 -> T[0]
    if (did == 0) { c_ds = 0u; c_dd = 0u; }
    R[b * LL + t]           = c_ss | (c_sd << 16);
    R[BB * LL + b * LL + t] = c_ds | (c_dd << 16);
}

// ---- Kernel B2: pure streamer. out4[g] = T4[lo*16+q] + T4[hi*16+q].
// Zero LDS, tiny VGPR -> 32 waves/CU. Writes perfectly coalesced.
__global__ __launch_bounds__(256) void stream_out(
    const unsigned int* __restrict__ R, const float* __restrict__ T,
    float4* __restrict__ out4)
{
    const float4* T4 = (const float4*)T;
    int g = blockIdx.x * 256 + threadIdx.x;
    const int stride = gridDim.x * 256;
    for (; g < NT4; g += stride) {
        const unsigned int r = R[g >> 4];
        const int q = g & 15;
        const float4 x = T4[(r & 0xFFFFu) * 16 + q];
        const float4 y = T4[(r >> 16) * 16 + q];
        float4 v;
        v.x = x.x + y.x; v.y = x.y + y.y; v.z = x.z + y.z; v.w = x.w + y.w;
        out4[g] = v;
    }
}

extern "C" void kernel_launch(void* const* d_in, const int* in_sizes, int n_in,
                              void* d_out, int out_size, void* d_ws, size_t ws_size,
                              hipStream_t stream) {
    const int*   src_ids = (const int*)d_in[0];
    const int*   dst_ids = (const int*)d_in[1];
    const float* W1      = (const float*)d_in[2];   // (64,1)
    const float* b1      = (const float*)d_in[3];   // (64,)
    const float* W2      = (const float*)d_in[4];   // (64,64)
    const float* b2      = (const float*)d_in[5];   // (64,)

    float*        T = (float*)d_ws;                               // 131,328 B
    unsigned int* R = (unsigned int*)((char*)d_ws + (256 << 10)); // 1 MB at +256 KB

    build_table<<<dim3(129), dim3(256), 0, stream>>>(W1, b1, W2, b2, T);
    count_rows<<<dim3(BB), dim3(512), 0, stream>>>(src_ids, dst_ids, R);
    stream_out<<<dim3(2048), dim3(256), 0, stream>>>(R, T, (float4*)d_out);
}

// Round 5
// 91.198 us; speedup vs baseline: 1.0328x; 1.0328x over previous
//
#include <hip/hip_runtime.h>

#define BB  256
#define LL  512
#define DD  64
#define NID 10000
#define NW  (NID / 2)        // packed u16 pairs per histogram

// ---- Kernel A: T[a][e] = sum_d relu(a*W1[d]+b1[d]) * W2[e][d] + b2[e], a in [0,512]
__global__ __launch_bounds__(256) void build_table(
    const float* __restrict__ W1, const float* __restrict__ b1,
    const float* __restrict__ W2, const float* __restrict__ b2,
    float* __restrict__ T)
{
    __shared__ float w2l[DD][DD + 1];
    __shared__ float hsh[4][DD];
    const int t = threadIdx.x;
    const int w = t >> 6;
    const int e = t & 63;
    for (int i = t; i < DD * DD; i += 256)
        w2l[i >> 6][i & 63] = W2[i];
    const int a = blockIdx.x * 4 + w;   // 0..515
    hsh[w][e] = fmaxf((float)a * W1[e] + b1[e], 0.0f);
    __syncthreads();
    if (a <= LL) {
        float acc = b2[e];
#pragma unroll
        for (int d = 0; d < DD; ++d)
            acc = fmaf(hsh[w][d], w2l[e][d], acc);
        T[a * DD + e] = acc;
    }
}

// ---- Kernel B (fused): per-batch histogram -> counts in LDS -> gather T -> stream out.
// 1024 threads: thread t owns row t of the batch's 1024 output rows
// (rows 0..511 = src positions, 512..1023 = dst positions) for counting;
// streaming uses 16 lanes per row for coalesced 1 KB/wave stores.
__global__ __launch_bounds__(1024) void count_stream(
    const int* __restrict__ src_ids, const int* __restrict__ dst_ids,
    const float* __restrict__ T, float4* __restrict__ out4)
{
    __shared__ unsigned int hs[NW];        // 20000 B, src histogram (2 u16 / word)
    __shared__ unsigned int hd[NW];        // 20000 B, dst histogram
    __shared__ int ids[2 * LL];            // 4 KB
    __shared__ unsigned int cnt[2 * LL];   // 4 KB packed (c_in_src | c_in_dst<<16)

    const int t = threadIdx.x;             // 0..1023
    const int b = blockIdx.x;

    // zero histograms (uint4-wide)
    uint4* z1 = (uint4*)hs;
    uint4* z2 = (uint4*)hd;
    const uint4 z = make_uint4(0u, 0u, 0u, 0u);
    for (int i = t; i < NW / 4; i += 1024) { z1[i] = z; z2[i] = z; }

    ids[t] = (t < LL) ? src_ids[b * LL + t] : dst_ids[b * LL + (t - LL)];
    __syncthreads();

    const int id = ids[t];
    unsigned int* h = (t < LL) ? hs : hd;  // waves 0-7 insert src, 8-15 insert dst
    atomicAdd(&h[id >> 1], 1u << ((id & 1) * 16));
    __syncthreads();

    unsigned int c0 = (hs[id >> 1] >> ((id & 1) * 16)) & 0xFFFFu;  // count in src seq
    unsigned int c1 = (hd[id >> 1] >> ((id & 1) * 16)) & 0xFFFFu;  // count in dst seq
    if (id == 0) { c0 = 0u; c1 = 0u; }     // padding -> app forced to 0 -> T[0]
    cnt[t] = c0 | (c1 << 16);
    __syncthreads();

    // Stream: out row r feat = T[lo] + T[hi]. 16 float4 per row; 64 rows per pass.
    const float4* T4 = (const float4*)T;
    const int q     = t & 15;
    const int rbase = t >> 4;              // 0..63
    float4* osrc = out4 + (size_t)b * LL * 16;
    float4* odst = out4 + (size_t)BB * LL * 16 + (size_t)b * LL * 16;

#pragma unroll 4
    for (int pass = 0; pass < 8; ++pass) {             // src rows 0..511
        const int r = pass * 64 + rbase;
        const unsigned int c = cnt[r];
        const float4 x = T4[(c & 0xFFFFu) * 16 + q];
        const float4 y = T4[(c >> 16) * 16 + q];
        float4 v;
        v.x = x.x + y.x; v.y = x.y + y.y; v.z = x.z + y.z; v.w = x.w + y.w;
        osrc[r * 16 + q] = v;
    }
#pragma unroll 4
    for (int pass = 8; pass < 16; ++pass) {            // dst rows 512..1023
        const int r = pass * 64 + rbase;
        const unsigned int c = cnt[r];
        const float4 x = T4[(c & 0xFFFFu) * 16 + q];
        const float4 y = T4[(c >> 16) * 16 + q];
        float4 v;
        v.x = x.x + y.x; v.y = x.y + y.y; v.z = x.z + y.z; v.w = x.w + y.w;
        odst[(r - LL) * 16 + q] = v;
    }
}

extern "C" void kernel_launch(void* const* d_in, const int* in_sizes, int n_in,
                              void* d_out, int out_size, void* d_ws, size_t ws_size,
                              hipStream_t stream) {
    const int*   src_ids = (const int*)d_in[0];
    const int*   dst_ids = (const int*)d_in[1];
    const float* W1      = (const float*)d_in[2];   // (64,1)
    const float* b1      = (const float*)d_in[3];   // (64,)
    const float* W2      = (const float*)d_in[4];   // (64,64)
    const float* b2      = (const float*)d_in[5];   // (64,)

    float* T = (float*)d_ws;                        // 513*64*4 = 131,328 B

    build_table<<<dim3(129), dim3(256), 0, stream>>>(W1, b1, W2, b2, T);
    count_stream<<<dim3(BB), dim3(1024), 0, stream>>>(src_ids, dst_ids, T, (float4*)d_out);
}